// Round 1
// baseline (1500.706 us; speedup 1.0000x reference)
//
#include <hip/hip_runtime.h>

#define NN 50000
#define NE 640000

typedef __bf16 bf16x8 __attribute__((ext_vector_type(8)));
typedef short  short8 __attribute__((ext_vector_type(8)));
typedef float  f32x4  __attribute__((ext_vector_type(4)));

__device__ __forceinline__ short f2bf(float v) {
  unsigned u = __builtin_bit_cast(unsigned, v);
  u = (u + 0x7FFFu + ((u >> 16) & 1u)) >> 16;   // RNE
  return (short)u;
}
__device__ __forceinline__ float bf2f(short s) {
  unsigned u = ((unsigned)(unsigned short)s) << 16;
  return __builtin_bit_cast(float, u);
}
__device__ __forceinline__ float silu_f(float v) {
  return v / (1.0f + __expf(-v));
}
__device__ __forceinline__ bf16x8 ld8(const short* p) {
  return *(const bf16x8*)(p);
}

// ---------------- prep: bf16 weight transposes + str convert ----------------
__global__ void egcl_prep(const float* __restrict__ mw1, const float* __restrict__ mw2,
                          const float* __restrict__ tw1, const float* __restrict__ tw2,
                          const float* __restrict__ pw1, const float* __restrict__ pw2,
                          const float* __restrict__ strf,
                          short* __restrict__ w1t, short* __restrict__ w2t,
                          short* __restrict__ t1t, short* __restrict__ t2t,
                          short* __restrict__ p1t, short* __restrict__ p2t,
                          short* __restrict__ strb)
{
  const int S1 = 65536, S2 = 98304, S3 = 32768, SS = NN * 128;
  const int total = 4 * S1 + S2 + S3 + SS;
  int stride = gridDim.x * blockDim.x;
  for (int i = blockIdx.x * blockDim.x + threadIdx.x; i < total; i += stride) {
    int j = i;
    if (j < S1) { int n = j >> 8, k = j & 255; w1t[j] = f2bf(mw1[k * 256 + n]); continue; }
    j -= S1;
    if (j < S1) { int n = j >> 8, k = j & 255; w2t[j] = f2bf(mw2[k * 256 + n]); continue; }
    j -= S1;
    if (j < S1) { int n = j >> 8, k = j & 255; t1t[j] = f2bf(tw1[k * 256 + n]); continue; }
    j -= S1;
    if (j < S1) { int n = j >> 8, k = j & 255; t2t[j] = f2bf(tw2[k * 256 + n]); continue; }
    j -= S1;
    if (j < S2) { int n = j / 384, k = j - n * 384; p1t[j] = f2bf(pw1[k * 256 + n]); continue; }
    j -= S2;
    if (j < S3) { int n = j >> 8, k = j & 255; p2t[j] = f2bf(pw2[k * 128 + n]); continue; }
    j -= S3;
    strb[j] = f2bf(strf[j]);
  }
}

// ---------------- edge kernel ----------------
// 512 thr = 8 waves; 128 edges/wg; wave = (wm:2) x (wn:4); per-wave 4x4 tiles of 16x16.
// LDS Ab: [128][264] bf16, in-place between layers (read-all -> barrier -> write).

__device__ __forceinline__ void gemm_k256(const short* Ab, const short* __restrict__ WT,
                                          int wm, int wn, int l16, int quad,
                                          f32x4 acc[4][4])
{
#pragma unroll
  for (int nt = 0; nt < 4; ++nt)
#pragma unroll
    for (int mt = 0; mt < 4; ++mt)
      acc[nt][mt] = (f32x4)(0.0f);
#pragma unroll
  for (int ks = 0; ks < 8; ++ks) {
    const int kb = ks * 32 + quad * 8;
    bf16x8 b[4];
#pragma unroll
    for (int nt = 0; nt < 4; ++nt)
      b[nt] = ld8(WT + (wn * 64 + nt * 16 + l16) * 256 + kb);
#pragma unroll
    for (int mt = 0; mt < 4; ++mt) {
      bf16x8 a = ld8(Ab + (wm * 64 + mt * 16 + l16) * 264 + kb);
#pragma unroll
      for (int nt = 0; nt < 4; ++nt)
        acc[nt][mt] = __builtin_amdgcn_mfma_f32_16x16x32_bf16(a, b[nt], acc[nt][mt], 0, 0, 0);
    }
  }
}

template <bool L1>
__device__ __forceinline__ void epi_write(short* Ab, f32x4 acc[4][4],
                                          const float* __restrict__ bias,
                                          const float* __restrict__ w1last,
                                          const float* dist_s,
                                          int wm, int wn, int l16, int quad)
{
#pragma unroll
  for (int nt = 0; nt < 4; ++nt) {
    const int n = wn * 64 + nt * 16 + l16;
    const float bn = bias[n];
    float wd = 0.0f;
    if constexpr (L1) wd = w1last[n];
#pragma unroll
    for (int mt = 0; mt < 4; ++mt) {
#pragma unroll
      for (int r = 0; r < 4; ++r) {
        const int m = wm * 64 + mt * 16 + quad * 4 + r;
        float v = acc[nt][mt][r] + bn;
        if constexpr (L1) v += dist_s[m] * wd;
        Ab[m * 264 + n] = f2bf(silu_f(v));
      }
    }
  }
}

__global__ __launch_bounds__(512, 4)
void egcl_edge(const int* __restrict__ eidx, const float* __restrict__ coord,
               const short* __restrict__ strb,
               const short* __restrict__ w1t, const short* __restrict__ w2t,
               const short* __restrict__ t1t, const short* __restrict__ t2t,
               const float* __restrict__ msg_w1, const float* __restrict__ msg_b1,
               const float* __restrict__ msg_b2, const float* __restrict__ tr_b1,
               const float* __restrict__ tr_b2, const float* __restrict__ tr_w3,
               float* __restrict__ msg_sum, float* __restrict__ trans_sum,
               float* __restrict__ cnt)
{
  __shared__ short Ab[128 * 264];
  __shared__ int   rs_s[128];
  __shared__ float dist_s[128], cdx_s[128], cdy_s[128], cdz_s[128];

  const int tid  = threadIdx.x;
  const int lane = tid & 63, wave = tid >> 6;
  const int quad = lane >> 4, l16 = lane & 15;
  const int wm = wave >> 2, wn = wave & 3;
  const int e0 = blockIdx.x * 128;
  const int* __restrict__ rowp = eidx;
  const int* __restrict__ colp = eidx + NE;

  if (tid < 128) {
    int r = rowp[e0 + tid], c = colp[e0 + tid];
    rs_s[tid] = r;
    float dx = coord[r * 3 + 0] - coord[c * 3 + 0];
    float dy = coord[r * 3 + 1] - coord[c * 3 + 1];
    float dz = coord[r * 3 + 2] - coord[c * 3 + 2];
    cdx_s[tid] = dx; cdy_s[tid] = dy; cdz_s[tid] = dz;
    dist_s[tid] = dx * dx + dy * dy + dz * dz;
  }
  // stage A = [str[row] | str[col]] as bf16, 16B chunks
#pragma unroll
  for (int it = 0; it < 8; ++it) {
    int i = tid + it * 512;
    int e = i >> 5, c = i & 31;
    int node = (c < 16) ? rowp[e0 + e] : colp[e0 + e];
    short8 v = *(const short8*)(strb + node * 128 + (c & 15) * 8);
    *(short8*)(Ab + e * 264 + c * 8) = v;
  }
  __syncthreads();

  f32x4 acc[4][4];

  // L1: edge_in @ msg_w1 (+dist col) -> silu
  gemm_k256(Ab, w1t, wm, wn, l16, quad, acc);
  __syncthreads();
  epi_write<true>(Ab, acc, msg_b1, msg_w1 + 256 * 256, dist_s, wm, wn, l16, quad);
  __syncthreads();

  // L2: -> msg
  gemm_k256(Ab, w2t, wm, wn, l16, quad, acc);
  __syncthreads();
  epi_write<false>(Ab, acc, msg_b2, nullptr, dist_s, wm, wn, l16, quad);
  __syncthreads();

  // L3 gemm reads msg; then scatter msg before overwriting
  gemm_k256(Ab, t1t, wm, wn, l16, quad, acc);
  __syncthreads();
#pragma unroll 1
  for (int i = 0; i < 16; ++i) {
    const int e = wave * 16 + i;
    const int r = rs_s[e];
#pragma unroll
    for (int c4 = 0; c4 < 4; ++c4) {
      const int c = c4 * 64 + lane;
      atomicAdd(msg_sum + r * 256 + c, bf2f(Ab[e * 264 + c]));
    }
  }
  __syncthreads();
  epi_write<false>(Ab, acc, tr_b1, nullptr, dist_s, wm, wn, l16, quad);
  __syncthreads();

  // L4
  gemm_k256(Ab, t2t, wm, wn, l16, quad, acc);
  __syncthreads();
  epi_write<false>(Ab, acc, tr_b2, nullptr, dist_s, wm, wn, l16, quad);
  __syncthreads();

  // gate = T2 @ tr_w3 ; trans/cnt atomics
  {
    const int e = tid >> 2, p = tid & 3;
    const short* ap = Ab + e * 264 + p * 64;
    const float* wp = tr_w3 + p * 64;
    float s = 0.0f;
#pragma unroll
    for (int k = 0; k < 64; ++k) s += bf2f(ap[k]) * wp[k];
    s += __shfl_xor(s, 1);
    s += __shfl_xor(s, 2);
    if (p == 0) {
      const int r = rs_s[e];
      atomicAdd(trans_sum + r * 3 + 0, cdx_s[e] * s);
      atomicAdd(trans_sum + r * 3 + 1, cdy_s[e] * s);
      atomicAdd(trans_sum + r * 3 + 2, cdz_s[e] * s);
      atomicAdd(cnt + r, 1.0f);
    }
  }
}

// ---------------- node kernel ----------------
// 256 thr = 4 waves; 64 nodes/wg; K1=384 -> N=256 (silu), K2=256 -> N=128 (+residual)
__global__ __launch_bounds__(256, 3)
void egcl_node(const float* __restrict__ strf, const float* __restrict__ coord,
               const short* __restrict__ strb,
               const short* __restrict__ p1t, const short* __restrict__ p2t,
               const float* __restrict__ pb1, const float* __restrict__ pb2,
               const float* __restrict__ msg_sum, const float* __restrict__ trans_sum,
               const float* __restrict__ cnt, float* __restrict__ out)
{
  __shared__ short Ab[64 * 392];
  const int tid  = threadIdx.x;
  const int lane = tid & 63, wave = tid >> 6;
  const int quad = lane >> 4, l16 = lane & 15;
  const int n0 = blockIdx.x * 64;

#pragma unroll
  for (int it = 0; it < 4; ++it) {          // str cols 0..127
    int i = tid + it * 256;
    int m = i >> 4, c = i & 15;
    int n = n0 + m;
    short8 v = (short8)(short)0;
    if (n < NN) v = *(const short8*)(strb + n * 128 + c * 8);
    *(short8*)(Ab + m * 392 + c * 8) = v;
  }
#pragma unroll
  for (int it = 0; it < 8; ++it) {          // msg_sum cols 128..383
    int i = tid + it * 256;
    int m = i >> 5, c = i & 31;
    int n = n0 + m;
    short8 v = (short8)(short)0;
    if (n < NN) {
      const float* src = msg_sum + n * 256 + c * 8;
#pragma unroll
      for (int j = 0; j < 8; ++j) v[j] = f2bf(src[j]);
    }
    *(short8*)(Ab + m * 392 + 128 + c * 8) = v;
  }
  __syncthreads();

  f32x4 acc[4][4];
#pragma unroll
  for (int nt = 0; nt < 4; ++nt)
#pragma unroll
    for (int mt = 0; mt < 4; ++mt) acc[nt][mt] = (f32x4)(0.0f);
#pragma unroll
  for (int ks = 0; ks < 12; ++ks) {
    const int kb = ks * 32 + quad * 8;
    bf16x8 b[4];
#pragma unroll
    for (int nt = 0; nt < 4; ++nt)
      b[nt] = ld8(p1t + (wave * 64 + nt * 16 + l16) * 384 + kb);
#pragma unroll
    for (int mt = 0; mt < 4; ++mt) {
      bf16x8 a = ld8(Ab + (mt * 16 + l16) * 392 + kb);
#pragma unroll
      for (int nt = 0; nt < 4; ++nt)
        acc[nt][mt] = __builtin_amdgcn_mfma_f32_16x16x32_bf16(a, b[nt], acc[nt][mt], 0, 0, 0);
    }
  }
  __syncthreads();
#pragma unroll
  for (int nt = 0; nt < 4; ++nt) {
    const int n = wave * 64 + nt * 16 + l16;
    const float bn = pb1[n];
#pragma unroll
    for (int mt = 0; mt < 4; ++mt)
#pragma unroll
      for (int r = 0; r < 4; ++r) {
        const int m = mt * 16 + quad * 4 + r;
        Ab[m * 392 + n] = f2bf(silu_f(acc[nt][mt][r] + bn));
      }
  }
  __syncthreads();

  f32x4 a2[2][4];
#pragma unroll
  for (int nt = 0; nt < 2; ++nt)
#pragma unroll
    for (int mt = 0; mt < 4; ++mt) a2[nt][mt] = (f32x4)(0.0f);
#pragma unroll
  for (int ks = 0; ks < 8; ++ks) {
    const int kb = ks * 32 + quad * 8;
    bf16x8 b0 = ld8(p2t + (wave * 32 + l16) * 256 + kb);
    bf16x8 b1 = ld8(p2t + (wave * 32 + 16 + l16) * 256 + kb);
#pragma unroll
    for (int mt = 0; mt < 4; ++mt) {
      bf16x8 a = ld8(Ab + (mt * 16 + l16) * 392 + kb);
      a2[0][mt] = __builtin_amdgcn_mfma_f32_16x16x32_bf16(a, b0, a2[0][mt], 0, 0, 0);
      a2[1][mt] = __builtin_amdgcn_mfma_f32_16x16x32_bf16(a, b1, a2[1][mt], 0, 0, 0);
    }
  }
#pragma unroll
  for (int nt = 0; nt < 2; ++nt) {
    const int c = wave * 32 + nt * 16 + l16;
    const float bc = pb2[c];
#pragma unroll
    for (int mt = 0; mt < 4; ++mt)
#pragma unroll
      for (int r = 0; r < 4; ++r) {
        const int m = mt * 16 + quad * 4 + r;
        const int n = n0 + m;
        if (n < NN) out[n * 128 + c] = strf[n * 128 + c] + a2[nt][mt][r] + bc;
      }
  }
  if (tid < 64) {
    const int n = n0 + tid;
    if (n < NN) {
      float cv = cnt[n]; if (cv < 1.0f) cv = 1.0f;
      float inv = 1.0f / cv;
      out[NN * 128 + n * 3 + 0] = coord[n * 3 + 0] + trans_sum[n * 3 + 0] * inv;
      out[NN * 128 + n * 3 + 1] = coord[n * 3 + 1] + trans_sum[n * 3 + 1] * inv;
      out[NN * 128 + n * 3 + 2] = coord[n * 3 + 2] + trans_sum[n * 3 + 2] * inv;
    }
  }
}

extern "C" void kernel_launch(void* const* d_in, const int* in_sizes, int n_in,
                              void* d_out, int out_size, void* d_ws, size_t ws_size,
                              hipStream_t stream)
{
  const int*   eidx   = (const int*)d_in[0];
  const float* strf   = (const float*)d_in[1];
  const float* coord  = (const float*)d_in[2];
  const float* msg_w1 = (const float*)d_in[3];
  const float* msg_b1 = (const float*)d_in[4];
  const float* msg_w2 = (const float*)d_in[5];
  const float* msg_b2 = (const float*)d_in[6];
  const float* tr_w1  = (const float*)d_in[7];
  const float* tr_b1  = (const float*)d_in[8];
  const float* tr_w2  = (const float*)d_in[9];
  const float* tr_b2  = (const float*)d_in[10];
  const float* tr_w3  = (const float*)d_in[11];
  const float* posi_w1 = (const float*)d_in[12];
  const float* posi_b1 = (const float*)d_in[13];
  const float* posi_w2 = (const float*)d_in[14];
  const float* posi_b2 = (const float*)d_in[15];
  float* out = (float*)d_out;

  char* ws = (char*)d_ws;
  float* msg_sum   = (float*)ws;                    // [N,256] f32
  float* trans_sum = msg_sum + NN * 256;            // [N,3]
  float* cnt       = trans_sum + NN * 3;            // [N]
  short* strb = (short*)(cnt + NN);                 // [N,128] bf16
  short* w1t  = strb + NN * 128;                    // [256][256]
  short* w2t  = w1t + 65536;
  short* t1t  = w2t + 65536;
  short* t2t  = t1t + 65536;
  short* p1t  = t2t + 65536;                        // [256][384]
  short* p2t  = p1t + 98304;                        // [128][256]

  hipMemsetAsync(ws, 0, (size_t)(NN * 256 + NN * 3 + NN) * 4, stream);
  egcl_prep<<<2048, 256, 0, stream>>>(msg_w1, msg_w2, tr_w1, tr_w2, posi_w1, posi_w2,
                                      strf, w1t, w2t, t1t, t2t, p1t, p2t, strb);
  egcl_edge<<<NE / 128, 512, 0, stream>>>(eidx, coord, strb, w1t, w2t, t1t, t2t,
                                          msg_w1, msg_b1, msg_b2, tr_b1, tr_b2, tr_w3,
                                          msg_sum, trans_sum, cnt);
  egcl_node<<<(NN + 63) / 64, 256, 0, stream>>>(strf, coord, strb, p1t, p2t,
                                                posi_b1, posi_b2,
                                                msg_sum, trans_sum, cnt, out);
}